// Round 9
// baseline (102.612 us; speedup 1.0000x reference)
//
#include <hip/hip_runtime.h>
#include <hip/hip_bf16.h>

// Problem geometry (fixed by the reference):
//   B=32, C=384, H=W=64 -> spatial = 4096 floats per (b,c) plane
//   R=8 reduced channels, combined = 24 values per batch
#define BATCH 32
#define CHAN 384
#define SPATIAL 4096
#define BC (BATCH * CHAN)        // 12288
#define RCH 8
#define NCOMB (3 * RCH)          // 24

// 2-group pipeline: 16 batches per group = 100.6 MB -> reuse distance fits L3
#define GPLANES (BC / 2)                 // 6144 planes per group
#define GN4 ((size_t)GPLANES * (SPATIAL / 4))   // 6,291,456 f4 per group

typedef float f32x4 __attribute__((ext_vector_type(4)));

// ---------------------------------------------------------------------------
// Kernel 1: fused global avg/max/min pool over one GROUP of planes.
// One WAVE (64 lanes) per (b,c) plane: 16 coalesced float4 loads per lane,
// reduce entirely in-wave (no LDS, no __syncthreads). 4 waves per block.
// ws layout: [0,BC) = sum, [BC,2BC) = max, [2BC,3BC) = min
// Plain (caching) loads: x should allocate in L3 for the epilogue re-read.
// ---------------------------------------------------------------------------
__global__ __launch_bounds__(256) void pool_kernel(const float* __restrict__ x,
                                                   float* __restrict__ ws,
                                                   int plane_off) {
    const int plane = plane_off + blockIdx.x * 4 + (threadIdx.x >> 6);
    const int lane = threadIdx.x & 63;
    const f32x4* p4 = (const f32x4*)(x + (size_t)plane * SPATIAL);

    f32x4 vs = {0.0f, 0.0f, 0.0f, 0.0f};
    f32x4 vmx = {-__builtin_inff(), -__builtin_inff(), -__builtin_inff(), -__builtin_inff()};
    f32x4 vmn = {__builtin_inff(), __builtin_inff(), __builtin_inff(), __builtin_inff()};
#pragma unroll
    for (int k = 0; k < 16; ++k) {
        f32x4 v = p4[lane + k * 64];
        vs += v;
        vmx.x = fmaxf(vmx.x, v.x); vmx.y = fmaxf(vmx.y, v.y);
        vmx.z = fmaxf(vmx.z, v.z); vmx.w = fmaxf(vmx.w, v.w);
        vmn.x = fminf(vmn.x, v.x); vmn.y = fminf(vmn.y, v.y);
        vmn.z = fminf(vmn.z, v.z); vmn.w = fminf(vmn.w, v.w);
    }
    float s = (vs.x + vs.y) + (vs.z + vs.w);
    float mx = fmaxf(fmaxf(vmx.x, vmx.y), fmaxf(vmx.z, vmx.w));
    float mn = fminf(fminf(vmn.x, vmn.y), fminf(vmn.z, vmn.w));
    // wave64 butterfly reduce
#pragma unroll
    for (int off = 32; off > 0; off >>= 1) {
        s += __shfl_xor(s, off);
        mx = fmaxf(mx, __shfl_xor(mx, off));
        mn = fminf(mn, __shfl_xor(mn, off));
    }
    if (lane == 0) {
        ws[plane] = s;
        ws[BC + plane] = mx;
        ws[2 * BC + plane] = mn;
    }
}

// ---------------------------------------------------------------------------
// Kernel 2: tiny "bottleneck MLP" -> logits [B, C].  One block per batch,
// 384 threads. Fully parallel: 24 output groups x 16 lanes each.
// ---------------------------------------------------------------------------
__global__ __launch_bounds__(CHAN) void logits_kernel(
    const float* __restrict__ pools,   // ws from kernel 1
    const float* __restrict__ W1,      // [8,384]
    const float* __restrict__ W2_1,    // [8,48]
    const float* __restrict__ W2_2,    // [8]
    const float* __restrict__ W3,      // [8,384]
    const float* __restrict__ Wfc,     // [384,24]
    float* __restrict__ logits)        // [B,C]
{
    const int b = blockIdx.x;
    const int tid = threadIdx.x;
    __shared__ float avg[CHAN], smx[CHAN], smn[CHAN], comb[NCOMB];

    avg[tid] = pools[b * CHAN + tid] * (1.0f / (float)SPATIAL);
    smx[tid] = pools[BC + b * CHAN + tid];
    smn[tid] = pools[2 * BC + b * CHAN + tid];
    __syncthreads();

    const int gid = tid >> 4;       // 0..23 output group
    const int l16 = tid & 15;       // lane within group
    float a = 0.0f;
    if (gid < RCH) {                // avg path: 384-dot, 24 elems/lane
        const int r = gid;
#pragma unroll
        for (int k = 0; k < CHAN / 16; ++k) {
            const int c = l16 + k * 16;
            a += avg[c] * W1[r * CHAN + c];
        }
    } else if (gid < 2 * RCH) {     // max path: grouped 48-dot, 3 elems/lane
        const int r = gid - RCH;
#pragma unroll
        for (int k = 0; k < 3; ++k) {
            const int g = l16 + k * 16;
            a += smx[r * (CHAN / RCH) + g] * W2_1[r * (CHAN / RCH) + g];
        }
    } else {                        // min path: 384-dot
        const int r = gid - 2 * RCH;
#pragma unroll
        for (int k = 0; k < CHAN / 16; ++k) {
            const int c = l16 + k * 16;
            a += smn[c] * W3[r * CHAN + c];
        }
    }
    // reduce within the 16-lane group (stays inside one wave: 16 | 64)
#pragma unroll
    for (int off = 8; off > 0; off >>= 1) a += __shfl_xor(a, off);
    if (l16 == 0) {
        if (gid >= RCH && gid < 2 * RCH) a *= W2_2[gid - RCH];
        comb[gid] = a;
    }
    __syncthreads();

    float l = 0.0f;
#pragma unroll
    for (int j = 0; j < NCOMB; ++j) l += comb[j] * Wfc[tid * NCOMB + j];
    logits[b * CHAN + tid] = l;
}

// ---------------------------------------------------------------------------
// Kernel 3: out = sigmoid(x + logits[b,c]) over one GROUP (16 batches).
// The group's x slab (100.6 MB) was read by its pool kernel at most ~100 MB
// of traffic ago -> fits the 256 MB Infinity Cache irrespective of the
// replacement policy -> reads are L3 hits; kernel becomes write-bound.
// GN4 = 12 * (2048*256): 12 passes, unroll 2, no tail. x read temporal;
// out store nontemporal (never re-read; don't evict the other group's x).
// ---------------------------------------------------------------------------
__global__ __launch_bounds__(256) void add_sig_kernel(
    const float* __restrict__ x,
    const float* __restrict__ logits,
    float* __restrict__ out,
    size_t base)                      // f4 offset of the group start
{
    const size_t stride = 2048 * 256;
    const size_t tid = blockIdx.x * (size_t)blockDim.x + threadIdx.x;
    const f32x4* x4 = (const f32x4*)x;
    f32x4* o4 = (f32x4*)out;
#pragma unroll
    for (int p = 0; p < 12; p += 2) {
        const size_t i0 = base + (size_t)p * stride + tid;
        const size_t i1 = i0 + stride;
        f32x4 v0 = x4[i0];
        f32x4 v1 = x4[i1];
        const float l0 = logits[(int)(i0 >> 10)];
        const float l1 = logits[(int)(i1 >> 10)];
        f32x4 r0, r1;
        r0.x = __builtin_amdgcn_rcpf(1.0f + __expf(-(v0.x + l0)));
        r0.y = __builtin_amdgcn_rcpf(1.0f + __expf(-(v0.y + l0)));
        r0.z = __builtin_amdgcn_rcpf(1.0f + __expf(-(v0.z + l0)));
        r0.w = __builtin_amdgcn_rcpf(1.0f + __expf(-(v0.w + l0)));
        r1.x = __builtin_amdgcn_rcpf(1.0f + __expf(-(v1.x + l1)));
        r1.y = __builtin_amdgcn_rcpf(1.0f + __expf(-(v1.y + l1)));
        r1.z = __builtin_amdgcn_rcpf(1.0f + __expf(-(v1.z + l1)));
        r1.w = __builtin_amdgcn_rcpf(1.0f + __expf(-(v1.w + l1)));
        __builtin_nontemporal_store(r0, &o4[i0]);
        __builtin_nontemporal_store(r1, &o4[i1]);
    }
}

// ---------------------------------------------------------------------------
// Launch order: pool(g0); pool(g1); logits(all); epi(g0); epi(g1).
// epi(g0)'s re-read of x[g0] has only pool(g1)'s ~100 MB in between;
// epi(g1)'s re-read has only logits + epi(g0) (L3 hits + NT writes).
// ---------------------------------------------------------------------------
extern "C" void kernel_launch(void* const* d_in, const int* in_sizes, int n_in,
                              void* d_out, int out_size, void* d_ws, size_t ws_size,
                              hipStream_t stream) {
    const float* x    = (const float*)d_in[0];
    const float* W1   = (const float*)d_in[1];
    const float* W2_1 = (const float*)d_in[2];
    const float* W2_2 = (const float*)d_in[3];
    const float* W3   = (const float*)d_in[4];
    const float* Wfc  = (const float*)d_in[5];
    float* out = (float*)d_out;
    float* ws  = (float*)d_ws;          // needs 4*BC floats = 192 KiB
    float* logits = ws + 3 * BC;

    hipLaunchKernelGGL(pool_kernel, dim3(GPLANES / 4), dim3(256), 0, stream,
                       x, ws, 0);
    hipLaunchKernelGGL(pool_kernel, dim3(GPLANES / 4), dim3(256), 0, stream,
                       x, ws, GPLANES);
    hipLaunchKernelGGL(logits_kernel, dim3(BATCH), dim3(CHAN), 0, stream,
                       ws, W1, W2_1, W2_2, W3, Wfc, logits);
    hipLaunchKernelGGL(add_sig_kernel, dim3(2048), dim3(256), 0, stream,
                       x, logits, out, (size_t)0);
    hipLaunchKernelGGL(add_sig_kernel, dim3(2048), dim3(256), 0, stream,
                       x, logits, out, GN4);
}

// Round 10
// 95.282 us; speedup vs baseline: 1.0769x; 1.0769x over previous
//
#include <hip/hip_runtime.h>
#include <hip/hip_bf16.h>

// Problem geometry (fixed by the reference):
//   B=32, C=384, H=W=64 -> spatial = 4096 floats per (b,c) plane
//   R=8 reduced channels, combined = 24 values per batch
#define BATCH 32
#define CHAN 384
#define SPATIAL 4096
#define BC (BATCH * CHAN)        // 12288
#define RCH 8
#define NCOMB (3 * RCH)          // 24

typedef float f32x4 __attribute__((ext_vector_type(4)));

// ---------------------------------------------------------------------------
// Kernel 1: fused global avg/max/min pool.
// One WAVE (64 lanes) per (b,c) plane: 16 coalesced float4 loads per lane,
// reduce entirely in-wave (no LDS, no __syncthreads). 4 waves per block.
// ws layout: [0,BC) = sum, [BC,2BC) = max, [2BC,3BC) = min
// Plain (caching) loads: partial L3 residency helps kernel 3 (~9 us measured).
// ---------------------------------------------------------------------------
__global__ __launch_bounds__(256) void pool_kernel(const float* __restrict__ x,
                                                   float* __restrict__ ws) {
    const int plane = blockIdx.x * 4 + (threadIdx.x >> 6);   // (b,c) index
    const int lane = threadIdx.x & 63;
    const f32x4* p4 = (const f32x4*)(x + (size_t)plane * SPATIAL);

    f32x4 vs = {0.0f, 0.0f, 0.0f, 0.0f};
    f32x4 vmx = {-__builtin_inff(), -__builtin_inff(), -__builtin_inff(), -__builtin_inff()};
    f32x4 vmn = {__builtin_inff(), __builtin_inff(), __builtin_inff(), __builtin_inff()};
#pragma unroll
    for (int k = 0; k < 16; ++k) {
        f32x4 v = p4[lane + k * 64];
        vs += v;
        vmx.x = fmaxf(vmx.x, v.x); vmx.y = fmaxf(vmx.y, v.y);
        vmx.z = fmaxf(vmx.z, v.z); vmx.w = fmaxf(vmx.w, v.w);
        vmn.x = fminf(vmn.x, v.x); vmn.y = fminf(vmn.y, v.y);
        vmn.z = fminf(vmn.z, v.z); vmn.w = fminf(vmn.w, v.w);
    }
    float s = (vs.x + vs.y) + (vs.z + vs.w);
    float mx = fmaxf(fmaxf(vmx.x, vmx.y), fmaxf(vmx.z, vmx.w));
    float mn = fminf(fminf(vmn.x, vmn.y), fminf(vmn.z, vmn.w));
    // wave64 butterfly reduce
#pragma unroll
    for (int off = 32; off > 0; off >>= 1) {
        s += __shfl_xor(s, off);
        mx = fmaxf(mx, __shfl_xor(mx, off));
        mn = fminf(mn, __shfl_xor(mn, off));
    }
    if (lane == 0) {
        ws[plane] = s;
        ws[BC + plane] = mx;
        ws[2 * BC + plane] = mn;
    }
}

// ---------------------------------------------------------------------------
// Kernel 2: tiny "bottleneck MLP" -> logits [B, C].  One block per batch,
// 384 threads. Fully parallel: 24 output groups x 16 lanes each.
// ---------------------------------------------------------------------------
__global__ __launch_bounds__(CHAN) void logits_kernel(
    const float* __restrict__ pools,   // ws from kernel 1
    const float* __restrict__ W1,      // [8,384]
    const float* __restrict__ W2_1,    // [8,48]
    const float* __restrict__ W2_2,    // [8]
    const float* __restrict__ W3,      // [8,384]
    const float* __restrict__ Wfc,     // [384,24]
    float* __restrict__ logits)        // [B,C]
{
    const int b = blockIdx.x;
    const int tid = threadIdx.x;
    __shared__ float avg[CHAN], smx[CHAN], smn[CHAN], comb[NCOMB];

    avg[tid] = pools[b * CHAN + tid] * (1.0f / (float)SPATIAL);
    smx[tid] = pools[BC + b * CHAN + tid];
    smn[tid] = pools[2 * BC + b * CHAN + tid];
    __syncthreads();

    const int gid = tid >> 4;       // 0..23 output group
    const int l16 = tid & 15;       // lane within group
    float a = 0.0f;
    if (gid < RCH) {                // avg path: 384-dot, 24 elems/lane
        const int r = gid;
#pragma unroll
        for (int k = 0; k < CHAN / 16; ++k) {
            const int c = l16 + k * 16;
            a += avg[c] * W1[r * CHAN + c];
        }
    } else if (gid < 2 * RCH) {     // max path: grouped 48-dot, 3 elems/lane
        const int r = gid - RCH;
#pragma unroll
        for (int k = 0; k < 3; ++k) {
            const int g = l16 + k * 16;
            a += smx[r * (CHAN / RCH) + g] * W2_1[r * (CHAN / RCH) + g];
        }
    } else {                        // min path: 384-dot
        const int r = gid - 2 * RCH;
#pragma unroll
        for (int k = 0; k < CHAN / 16; ++k) {
            const int c = l16 + k * 16;
            a += smn[c] * W3[r * CHAN + c];
        }
    }
    // reduce within the 16-lane group (stays inside one wave: 16 | 64)
#pragma unroll
    for (int off = 8; off > 0; off >>= 1) a += __shfl_xor(a, off);
    if (l16 == 0) {
        if (gid >= RCH && gid < 2 * RCH) a *= W2_2[gid - RCH];
        comb[gid] = a;
    }
    __syncthreads();

    float l = 0.0f;
#pragma unroll
    for (int j = 0; j < NCOMB; ++j) l += comb[j] * Wfc[tid * NCOMB + j];
    logits[b * CHAN + tid] = l;
}

// ---------------------------------------------------------------------------
// Kernel 3: out = sigmoid(x + logits[b,c]), elementwise, float4-vectorized.
// x read is PLAIN/temporal (partial L3 hits, +9 us vs nontemporal, measured
// R5->R6). out store nontemporal (never re-read; don't evict x from L3).
// n4 = 24 * (2048*256): exactly 24 strided passes -> unroll 2, no tail.
// ---------------------------------------------------------------------------
__global__ __launch_bounds__(256) void add_sig_kernel(
    const float* __restrict__ x,
    const float* __restrict__ logits,
    float* __restrict__ out)
{
    const size_t n4 = (size_t)BC * (SPATIAL / 4);   // 12,582,912 float4
    const size_t stride = 2048 * 256;
    size_t i = blockIdx.x * (size_t)blockDim.x + threadIdx.x;
    const f32x4* x4 = (const f32x4*)x;
    f32x4* o4 = (f32x4*)out;
    for (; i < n4; i += 2 * stride) {
        const size_t i2 = i + stride;
        f32x4 v0 = x4[i];
        f32x4 v1 = x4[i2];
        const float l0 = logits[(int)(i >> 10)];
        const float l1 = logits[(int)(i2 >> 10)];
        f32x4 o0, o1;
        o0.x = __builtin_amdgcn_rcpf(1.0f + __expf(-(v0.x + l0)));
        o0.y = __builtin_amdgcn_rcpf(1.0f + __expf(-(v0.y + l0)));
        o0.z = __builtin_amdgcn_rcpf(1.0f + __expf(-(v0.z + l0)));
        o0.w = __builtin_amdgcn_rcpf(1.0f + __expf(-(v0.w + l0)));
        o1.x = __builtin_amdgcn_rcpf(1.0f + __expf(-(v1.x + l1)));
        o1.y = __builtin_amdgcn_rcpf(1.0f + __expf(-(v1.y + l1)));
        o1.z = __builtin_amdgcn_rcpf(1.0f + __expf(-(v1.z + l1)));
        o1.w = __builtin_amdgcn_rcpf(1.0f + __expf(-(v1.w + l1)));
        __builtin_nontemporal_store(o0, &o4[i]);
        __builtin_nontemporal_store(o1, &o4[i2]);
    }
}

// ---------------------------------------------------------------------------
extern "C" void kernel_launch(void* const* d_in, const int* in_sizes, int n_in,
                              void* d_out, int out_size, void* d_ws, size_t ws_size,
                              hipStream_t stream) {
    const float* x    = (const float*)d_in[0];
    const float* W1   = (const float*)d_in[1];
    const float* W2_1 = (const float*)d_in[2];
    const float* W2_2 = (const float*)d_in[3];
    const float* W3   = (const float*)d_in[4];
    const float* Wfc  = (const float*)d_in[5];
    float* out = (float*)d_out;
    float* ws  = (float*)d_ws;          // needs 4*BC floats = 192 KiB
    float* logits = ws + 3 * BC;

    hipLaunchKernelGGL(pool_kernel, dim3(BC / 4), dim3(256), 0, stream, x, ws);
    hipLaunchKernelGGL(logits_kernel, dim3(BATCH), dim3(CHAN), 0, stream,
                       ws, W1, W2_1, W2_2, W3, Wfc, logits);
    hipLaunchKernelGGL(add_sig_kernel, dim3(2048), dim3(256), 0, stream,
                       x, logits, out);
}